// Round 10
// baseline (231.384 us; speedup 1.0000x reference)
//
#include <hip/hip_runtime.h>

// Problem constants (from reference config)
#define BATCH 4
#define NCAM  6
#define DNUM  41
#define FHN   8
#define FWN   22
#define CCH   128
#define NXV   200
#define NYV   200
#define NXY   40000      // NXV*NYV
#define NPTS  173184     // BATCH*NCAM*DNUM*FHN*FWN
#define SBINS (BATCH * NXY)   // 160000 voxel bins
#define CAP   64         // bucket capacity per bin
#define OVF_MAX 8192     // overflow side-list capacity
#define NSTAGE 8         // bucket slots staged in LDS per bin

struct Mats {
    float iR[9];    // inv(post_rots), fp32 LU (gesv-style)
    float comb[9];  // rots @ inv(intrins), fp32 no-FMA matmul
    float tr[3];    // trans
    float pt[3];    // post_trans
};

// Register-only fp32 3x3 inverse: IDENTICAL fp operation sequence to LAPACK
// sgesv-style LU (partial pivot, reciprocal-scaled, unit-lower fwd solve,
// reciprocal back solve), but with named scalars + branch pivot swaps so
// nothing spills to scratch. Swaps are pure data movement -> bit-exact
// equal to the array version. No FMA (contract off).
__device__ __forceinline__ void inv3x3_f32_gesv_reg(const float* __restrict__ Ain,
                                                    float* __restrict__ inv) {
#pragma clang fp contract(off)
    float a00=Ain[0], a01=Ain[1], a02=Ain[2];
    float a10=Ain[3], a11=Ain[4], a12=Ain[5];
    float a20=Ain[6], a21=Ain[7], a22=Ain[8];
    int p0, p1;
    // j=0: pivot among rows 0..2 on column 0
    {
        float amax = fabsf(a00); p0 = 0;
        float v1 = fabsf(a10); if (v1 > amax) { amax = v1; p0 = 1; }
        float v2 = fabsf(a20); if (v2 > amax) { p0 = 2; }
        if (p0 == 1)      { float t; t=a00;a00=a10;a10=t; t=a01;a01=a11;a11=t; t=a02;a02=a12;a12=t; }
        else if (p0 == 2) { float t; t=a00;a00=a20;a20=t; t=a01;a01=a21;a21=t; t=a02;a02=a22;a22=t; }
        float rd = 1.0f / a00;
        a10 = a10 * rd; a20 = a20 * rd;
        a11 = a11 - a10 * a01; a12 = a12 - a10 * a02;
        a21 = a21 - a20 * a01; a22 = a22 - a20 * a02;
    }
    // j=1: pivot among rows 1..2 on column 1 (full-row swap incl. multipliers)
    {
        float amax = fabsf(a11); p1 = 1;
        float v2 = fabsf(a21); if (v2 > amax) { p1 = 2; }
        if (p1 == 2) { float t; t=a10;a10=a20;a20=t; t=a11;a11=a21;a21=t; t=a12;a12=a22;a22=t; }
        float rd = 1.0f / a11;
        a21 = a21 * rd;
        a22 = a22 - a21 * a12;
    }
    float rd0 = 1.0f / a00, rd1 = 1.0f / a11, rd2 = 1.0f / a22;
#pragma unroll
    for (int c = 0; c < 3; ++c) {
        float b0 = (c==0)?1.0f:0.0f, b1 = (c==1)?1.0f:0.0f, b2 = (c==2)?1.0f:0.0f;
        // apply pivots: swap b0<->b[p0], then b1<->b[p1]
        if (p0 == 1)      { float t=b0; b0=b1; b1=t; }
        else if (p0 == 2) { float t=b0; b0=b2; b2=t; }
        if (p1 == 2)      { float t=b1; b1=b2; b2=t; }
        // unit-lower forward solve
        b1 = b1 - a10 * b0;
        b2 = b2 - a20 * b0;
        b2 = b2 - a21 * b1;
        // reciprocal back solve
        b2 = b2 * rd2;
        b0 = b0 - a02 * b2;
        b1 = b1 - a12 * b2;
        b1 = b1 * rd1;
        b0 = b0 - a01 * b1;
        b0 = b0 * rd0;
        inv[0 + c] = b0; inv[3 + c] = b1; inv[6 + c] = b2;
    }
}

// One camera's Mats from the register-only gesv. Same fp sequence as ever.
__device__ __forceinline__ void compute_mats_reg(int i,
                                                 const float* __restrict__ rots,
                                                 const float* __restrict__ trans,
                                                 const float* __restrict__ intrins,
                                                 const float* __restrict__ post_rots,
                                                 const float* __restrict__ post_trans,
                                                 Mats* __restrict__ m) {
    inv3x3_f32_gesv_reg(post_rots + i * 9, m->iR);
    float invK[9];
    inv3x3_f32_gesv_reg(intrins + i * 9, invK);
    {
#pragma clang fp contract(off)
#pragma unroll
        for (int r = 0; r < 3; ++r)
#pragma unroll
            for (int c = 0; c < 3; ++c) {
                float s = rots[i * 9 + r * 3 + 0] * invK[0 * 3 + c];
                s = s + rots[i * 9 + r * 3 + 1] * invK[1 * 3 + c];
                s = s + rots[i * 9 + r * 3 + 2] * invK[2 * 3 + c];
                m->comb[r * 3 + c] = s;
            }
    }
    for (int k = 0; k < 3; ++k) {
        m->tr[k] = trans[i * 3 + k];
        m->pt[k] = post_trans[i * 3 + k];
    }
}

// One-shot prep (fallback path only).
__global__ void prep_kernel(const float* __restrict__ rots,
                            const float* __restrict__ trans,
                            const float* __restrict__ intrins,
                            const float* __restrict__ post_rots,
                            const float* __restrict__ post_trans,
                            Mats* __restrict__ mats) {
    int i = threadIdx.x;
    if (i >= BATCH * NCAM) return;
    Mats m;
    compute_mats_reg(i, rots, trans, intrins, post_rots, post_trans, &m);
    mats[i] = m;
}

// Shared geometry: returns voxel flat index (b*NXY + gx*NYV + gy) or -1.
// BIT-EXACT fp sequence of the verified version — do not touch.
__device__ __forceinline__ int point_voxel(int p, const Mats* __restrict__ mats) {
#pragma clang fp contract(off)
    int w = p % FWN;
    int t = p / FWN;
    int h = t % FHN;
    t /= FHN;
    int d = t % DNUM;
    t /= DNUM;
    int n = t % NCAM;
    int b = t / NCAM;

    const Mats m = mats[b * NCAM + n];

    float u   = (float)((double)w * (351.0 / 21.0)); // linspace(0,351,22)
    float v   = (float)((double)h * (127.0 / 7.0));  // linspace(0,127,8)
    float dep = 4.0f + (float)d;                     // arange(4,45,1)

    float p0 = u - m.pt[0];
    float p1 = v - m.pt[1];
    float p2 = dep - m.pt[2];
    float q0 = m.iR[0] * p0; q0 = q0 + m.iR[1] * p1; q0 = q0 + m.iR[2] * p2;
    float q1 = m.iR[3] * p0; q1 = q1 + m.iR[4] * p1; q1 = q1 + m.iR[5] * p2;
    float q2 = m.iR[6] * p0; q2 = q2 + m.iR[7] * p1; q2 = q2 + m.iR[8] * p2;
    float r0 = q0 * q2;
    float r1 = q1 * q2;
    float e0 = m.comb[0] * r0; e0 = e0 + m.comb[1] * r1; e0 = e0 + m.comb[2] * q2; e0 = e0 + m.tr[0];
    float e1 = m.comb[3] * r0; e1 = e1 + m.comb[4] * r1; e1 = e1 + m.comb[5] * q2; e1 = e1 + m.tr[1];
    float e2 = m.comb[6] * r0; e2 = e2 + m.comb[7] * r1; e2 = e2 + m.comb[8] * q2; e2 = e2 + m.tr[2];

    float gxf = (e0 + 50.0f) / 0.5f;
    float gyf = (e1 + 50.0f) / 0.5f;
    float gzf = (e2 + 10.0f) / 20.0f;
    int gx = (int)gxf;
    int gy = (int)gyf;
    int gz = (int)gzf;
    if (gx < 0 || gx >= NXV || gy < 0 || gy >= NYV || gz < 0 || gz >= 1) return -1;
    return b * NXY + gx * NYV + gy;
}

// ---------------- Fused prep+bucket, then LDS-staged gather (3 enqueues) ----------------

// Per-block Mats in LDS (register-only gesv — no scratch, unlike R5's regression),
// then one thread per point -> fixed-capacity bucket via per-bin atomic cursor.
__global__ __launch_bounds__(256) void bucket_kernel(const float* __restrict__ rots,
                                                     const float* __restrict__ trans,
                                                     const float* __restrict__ intrins,
                                                     const float* __restrict__ post_rots,
                                                     const float* __restrict__ post_trans,
                                                     int* __restrict__ counts,
                                                     int* __restrict__ bucket,
                                                     int* __restrict__ ovfcnt,
                                                     int2* __restrict__ ovf) {
    __shared__ Mats smats[BATCH * NCAM];
    int t = threadIdx.x;
    if (t < BATCH * NCAM) {
        Mats m;
        compute_mats_reg(t, rots, trans, intrins, post_rots, post_trans, &m);
        smats[t] = m;
    }
    __syncthreads();
    int p = blockIdx.x * 256 + t;
    if (p < NPTS) {
        int vid = point_voxel(p, smats);
        if (vid >= 0) {
            int slot = atomicAdd(&counts[vid], 1);
            if (slot < CAP) {
                bucket[(size_t)vid * CAP + slot] = p;
            } else {
                int o = atomicAdd(ovfcnt, 1);
                if (o < OVF_MAX) ovf[o] = make_int2(vid, p);
            }
        }
    }
}

// Gather v5: block = 256 threads = (32 bins x 8 channel-groups). Stage counts AND
// the first NSTAGE bucket slots per bin into LDS with INDEPENDENT concurrent loads
// (one memory level, vs the old counts->idx->feats 3-level chain). Then each
// thread reads indices from LDS and issues ILP-batched feats loads (4 points x
// 4 float4 in flight). cnt>NSTAGE tail reads slots from global (rare).
// Summation order per bin = slot order (same as v3). Empty tiles short-circuit
// to a coalesced zero-write. Output written exactly once (no out memset).
__global__ __launch_bounds__(256) void gather5_kernel(const float* __restrict__ feats,
                                                      const int* __restrict__ counts,
                                                      const int* __restrict__ bucket,
                                                      const int* __restrict__ ovfcnt,
                                                      const int2* __restrict__ ovf,
                                                      float* __restrict__ out) {
    __shared__ float acc[32][129];      // scalar r/w: 2-lanes/bank both phases
    __shared__ int s_idx[32][9];        // stride 9 words: 2-way max on stage write
    __shared__ int s_cnt[32];
    int t = threadIdx.x;
    int j = t >> 3;                     // bin within tile   [0,32)
    int g = t & 7;                      // channel group     [0,8) x 16 ch
    int xy0 = blockIdx.x * 32;
    int b = blockIdx.y;
    int bin0 = b * NXY + xy0;
    int bin = bin0 + j;

    int novf = ovfcnt[0];               // independent broadcast load, issued early

    // --- stage (one memory level, all loads independent) ---
    if (t < 32) s_cnt[t] = counts[bin0 + t];
    s_idx[j][g] = bucket[(size_t)bin * CAP + g];   // unconditional; garbage if cnt==0 (unused)
    __syncthreads();

    int cntRaw = s_cnt[j];
    int cnt = cntRaw < CAP ? cntRaw : CAP;

    float4 a0 = {0.f,0.f,0.f,0.f}, a1 = a0, a2 = a0, a3 = a0;
    const float* fg = feats + g * 16;
    const int* bk = bucket + (size_t)bin * CAP;

    int kmax8 = cnt < NSTAGE ? cnt : NSTAGE;
    int k = 0;
    // staged path: indices from LDS, 4 points x 4 float4 = 16 loads in flight
    for (; k + 4 <= kmax8; k += 4) {
        int pp0 = s_idx[j][k], pp1 = s_idx[j][k+1], pp2 = s_idx[j][k+2], pp3 = s_idx[j][k+3];
        const float4* f0 = (const float4*)(fg + (size_t)pp0 * CCH);
        const float4* f1 = (const float4*)(fg + (size_t)pp1 * CCH);
        const float4* f2 = (const float4*)(fg + (size_t)pp2 * CCH);
        const float4* f3 = (const float4*)(fg + (size_t)pp3 * CCH);
        float4 v00 = f0[0], v01 = f0[1], v02 = f0[2], v03 = f0[3];
        float4 v10 = f1[0], v11 = f1[1], v12 = f1[2], v13 = f1[3];
        float4 v20 = f2[0], v21 = f2[1], v22 = f2[2], v23 = f2[3];
        float4 v30 = f3[0], v31 = f3[1], v32 = f3[2], v33 = f3[3];
        a0.x += v00.x; a0.y += v00.y; a0.z += v00.z; a0.w += v00.w;
        a1.x += v01.x; a1.y += v01.y; a1.z += v01.z; a1.w += v01.w;
        a2.x += v02.x; a2.y += v02.y; a2.z += v02.z; a2.w += v02.w;
        a3.x += v03.x; a3.y += v03.y; a3.z += v03.z; a3.w += v03.w;
        a0.x += v10.x; a0.y += v10.y; a0.z += v10.z; a0.w += v10.w;
        a1.x += v11.x; a1.y += v11.y; a1.z += v11.z; a1.w += v11.w;
        a2.x += v12.x; a2.y += v12.y; a2.z += v12.z; a2.w += v12.w;
        a3.x += v13.x; a3.y += v13.y; a3.z += v13.z; a3.w += v13.w;
        a0.x += v20.x; a0.y += v20.y; a0.z += v20.z; a0.w += v20.w;
        a1.x += v21.x; a1.y += v21.y; a1.z += v21.z; a1.w += v21.w;
        a2.x += v22.x; a2.y += v22.y; a2.z += v22.z; a2.w += v22.w;
        a3.x += v23.x; a3.y += v23.y; a3.z += v23.z; a3.w += v23.w;
        a0.x += v30.x; a0.y += v30.y; a0.z += v30.z; a0.w += v30.w;
        a1.x += v31.x; a1.y += v31.y; a1.z += v31.z; a1.w += v31.w;
        a2.x += v32.x; a2.y += v32.y; a2.z += v32.z; a2.w += v32.w;
        a3.x += v33.x; a3.y += v33.y; a3.z += v33.z; a3.w += v33.w;
    }
    for (; k < kmax8; ++k) {
        int p = s_idx[j][k];
        const float4* f4 = (const float4*)(fg + (size_t)p * CCH);
        float4 v0 = f4[0], v1 = f4[1], v2 = f4[2], v3 = f4[3];
        a0.x += v0.x; a0.y += v0.y; a0.z += v0.z; a0.w += v0.w;
        a1.x += v1.x; a1.y += v1.y; a1.z += v1.z; a1.w += v1.w;
        a2.x += v2.x; a2.y += v2.y; a2.z += v2.z; a2.w += v2.w;
        a3.x += v3.x; a3.y += v3.y; a3.z += v3.z; a3.w += v3.w;
    }
    // tail: slots beyond NSTAGE from global (rare), int4 batches then singles
    for (; k + 4 <= cnt; k += 4) {
        int4 pp = *(const int4*)(bk + k);
        const float4* f0 = (const float4*)(fg + (size_t)pp.x * CCH);
        const float4* f1 = (const float4*)(fg + (size_t)pp.y * CCH);
        const float4* f2 = (const float4*)(fg + (size_t)pp.z * CCH);
        const float4* f3 = (const float4*)(fg + (size_t)pp.w * CCH);
        float4 v00 = f0[0], v01 = f0[1], v02 = f0[2], v03 = f0[3];
        float4 v10 = f1[0], v11 = f1[1], v12 = f1[2], v13 = f1[3];
        float4 v20 = f2[0], v21 = f2[1], v22 = f2[2], v23 = f2[3];
        float4 v30 = f3[0], v31 = f3[1], v32 = f3[2], v33 = f3[3];
        a0.x += v00.x; a0.y += v00.y; a0.z += v00.z; a0.w += v00.w;
        a1.x += v01.x; a1.y += v01.y; a1.z += v01.z; a1.w += v01.w;
        a2.x += v02.x; a2.y += v02.y; a2.z += v02.z; a2.w += v02.w;
        a3.x += v03.x; a3.y += v03.y; a3.z += v03.z; a3.w += v03.w;
        a0.x += v10.x; a0.y += v10.y; a0.z += v10.z; a0.w += v10.w;
        a1.x += v11.x; a1.y += v11.y; a1.z += v11.z; a1.w += v11.w;
        a2.x += v12.x; a2.y += v12.y; a2.z += v12.z; a2.w += v12.w;
        a3.x += v13.x; a3.y += v13.y; a3.z += v13.z; a3.w += v13.w;
        a0.x += v20.x; a0.y += v20.y; a0.z += v20.z; a0.w += v20.w;
        a1.x += v21.x; a1.y += v21.y; a1.z += v21.z; a1.w += v21.w;
        a2.x += v22.x; a2.y += v22.y; a2.z += v22.z; a2.w += v22.w;
        a3.x += v23.x; a3.y += v23.y; a3.z += v23.z; a3.w += v23.w;
        a0.x += v30.x; a0.y += v30.y; a0.z += v30.z; a0.w += v30.w;
        a1.x += v31.x; a1.y += v31.y; a1.z += v31.z; a1.w += v31.w;
        a2.x += v32.x; a2.y += v32.y; a2.z += v32.z; a2.w += v32.w;
        a3.x += v33.x; a3.y += v33.y; a3.z += v33.z; a3.w += v33.w;
    }
    for (; k < cnt; ++k) {
        int p = bk[k];
        const float4* f4 = (const float4*)(fg + (size_t)p * CCH);
        float4 v0 = f4[0], v1 = f4[1], v2 = f4[2], v3 = f4[3];
        a0.x += v0.x; a0.y += v0.y; a0.z += v0.z; a0.w += v0.w;
        a1.x += v1.x; a1.y += v1.y; a1.z += v1.z; a1.w += v1.w;
        a2.x += v2.x; a2.y += v2.y; a2.z += v2.z; a2.w += v2.w;
        a3.x += v3.x; a3.y += v3.y; a3.z += v3.z; a3.w += v3.w;
    }

    // Overflow side list (normally empty).
    if (novf > 0) {
        if (novf > OVF_MAX) novf = OVF_MAX;
        for (int e = 0; e < novf; ++e) {
            int2 vp = ovf[e];
            if (vp.x == bin) {
                const float4* f4 = (const float4*)(fg + (size_t)vp.y * CCH);
                float4 v0 = f4[0], v1 = f4[1], v2 = f4[2], v3 = f4[3];
                a0.x += v0.x; a0.y += v0.y; a0.z += v0.z; a0.w += v0.w;
                a1.x += v1.x; a1.y += v1.y; a1.z += v1.z; a1.w += v1.w;
                a2.x += v2.x; a2.y += v2.y; a2.z += v2.z; a2.w += v2.w;
                a3.x += v3.x; a3.y += v3.y; a3.z += v3.z; a3.w += v3.w;
            }
        }
    }

    int nz = __syncthreads_count(cnt != 0);
    int tx = t & 31, tg = t >> 5;
    float* dst = out + (size_t)b * CCH * NXY + xy0 + tx;
    if (nz == 0) {
        // whole tile empty: coalesced zero-fill, skip LDS entirely
#pragma unroll
        for (int cc = 0; cc < 16; ++cc)
            dst[(size_t)(cc * 8 + tg) * NXY] = 0.0f;
        return;
    }

    float* row = &acc[j][g * 16];
    row[0]  = a0.x; row[1]  = a0.y; row[2]  = a0.z; row[3]  = a0.w;
    row[4]  = a1.x; row[5]  = a1.y; row[6]  = a1.z; row[7]  = a1.w;
    row[8]  = a2.x; row[9]  = a2.y; row[10] = a2.z; row[11] = a2.w;
    row[12] = a3.x; row[13] = a3.y; row[14] = a3.z; row[15] = a3.w;
    __syncthreads();

    // transposed write: wave = 2 chans x 128B contiguous segments — coalesced
#pragma unroll
    for (int cc = 0; cc < 16; ++cc) {
        int ch = cc * 8 + tg;
        dst[(size_t)ch * NXY] = acc[tx][ch];
    }
}

// ---------------- Fallback (tiny workspace): direct atomic scatter ----------------
__global__ __launch_bounds__(128) void scatter_direct_kernel(const float* __restrict__ feats,
                                                             const Mats* __restrict__ mats,
                                                             float* __restrict__ out) {
    int p = blockIdx.x;
    int vid = point_voxel(p, mats);
    if (vid < 0) return;
    int b  = vid / NXY;
    int xy = vid % NXY;
    int c = threadIdx.x;
    float f = feats[(size_t)p * CCH + c];
    atomicAdd(out + (size_t)(b * CCH + c) * NXY + xy, f);
}

extern "C" void kernel_launch(void* const* d_in, const int* in_sizes, int n_in,
                              void* d_out, int out_size, void* d_ws, size_t ws_size,
                              hipStream_t stream) {
    const float* cam_feats  = (const float*)d_in[0];
    const float* rots       = (const float*)d_in[1];
    const float* trans      = (const float*)d_in[2];
    const float* intrins    = (const float*)d_in[3];
    const float* post_rots  = (const float*)d_in[4];
    const float* post_trans = (const float*)d_in[5];
    float* out = (float*)d_out;

    // Workspace layout (256B-aligned; ~41.7 MB total)
    const size_t OFF_COUNTS = 4096;                             // SBINS ints
    const size_t OFF_OVFCNT = OFF_COUNTS + (size_t)SBINS * 4;   // 1 int (in the memset span)
    const size_t OFF_OVF    = OFF_OVFCNT + 256;                 // OVF_MAX int2
    const size_t OFF_BUCKET = OFF_OVF + (size_t)OVF_MAX * 8;    // SBINS*CAP ints
    const size_t WS_NEEDED  = OFF_BUCKET + (size_t)SBINS * CAP * 4;

    if (ws_size >= WS_NEEDED) {
        int*  counts = (int*)((char*)d_ws + OFF_COUNTS);
        int*  ovfcnt = (int*)((char*)d_ws + OFF_OVFCNT);
        int2* ovf    = (int2*)((char*)d_ws + OFF_OVF);
        int*  bucket = (int*)((char*)d_ws + OFF_BUCKET);

        // one memset covers counts + ovfcnt
        hipMemsetAsync(counts, 0, (size_t)SBINS * 4 + 256, stream);

        const int ptBlocks = (NPTS + 255) / 256;  // 677
        bucket_kernel<<<ptBlocks, 256, 0, stream>>>(rots, trans, intrins, post_rots,
                                                    post_trans, counts, bucket, ovfcnt, ovf);

        dim3 ggrid(NXY / 32, BATCH);              // (1250, 4)
        gather5_kernel<<<ggrid, 256, 0, stream>>>(cam_feats, counts, bucket, ovfcnt, ovf, out);
    } else {
        Mats* mats = (Mats*)d_ws;
        prep_kernel<<<1, 64, 0, stream>>>(rots, trans, intrins, post_rots, post_trans, mats);
        hipMemsetAsync(d_out, 0, (size_t)out_size * sizeof(float), stream);
        scatter_direct_kernel<<<NPTS, CCH, 0, stream>>>(cam_feats, mats, out);
    }
}